// Round 4
// baseline (716.334 us; speedup 1.0000x reference)
//
#include <hip/hip_runtime.h>
#include <hip/hip_fp16.h>
#include <math.h>

#define ITERS 12

// ---------------------------------------------------------------------------
// Kernel A: P = l2_normalize(X @ W^T + b) for both matrices (unchanged r3).
// Outputs: subP row-major [8192][64]; edgeT TRANSPOSED [64][8192].
// ---------------------------------------------------------------------------
__global__ __launch_bounds__(256) void proj_norm_kernel(
    const float* __restrict__ Xsub, const float* __restrict__ Xedge,
    const float* __restrict__ Wsub, const float* __restrict__ bsub,
    const float* __restrict__ Wedge, const float* __restrict__ bedge,
    float* __restrict__ subP, float* __restrict__ edgeT)
{
    const int mat = blockIdx.y;
    const float* X  = mat ? Xedge : Xsub;
    const float* W  = mat ? Wedge : Wsub;
    const float* Bv = mat ? bedge : bsub;

    const int r0 = blockIdx.x * 64;
    const int t  = threadIdx.x;
    const int tx = t & 15, ty = t >> 4;

    __shared__ float xs[64 * 68];
    __shared__ float ws[64 * 68];
    __shared__ float tr[64 * 68];

    float acc[4][4] = {};

    for (int ch = 0; ch < 8; ++ch) {
        const int kb = ch * 64;
#pragma unroll
        for (int i = 0; i < 4; ++i) {
            int e = t + 256 * i;
            int row = e & 63, kq = e >> 6;
            float4 xv = *(const float4*)(X + (size_t)(r0 + row) * 512 + kb + kq * 4);
            xs[(kq * 4 + 0) * 68 + row] = xv.x;
            xs[(kq * 4 + 1) * 68 + row] = xv.y;
            xs[(kq * 4 + 2) * 68 + row] = xv.z;
            xs[(kq * 4 + 3) * 68 + row] = xv.w;
            float4 wv = *(const float4*)(W + (size_t)row * 512 + kb + kq * 4);
            ws[(kq * 4 + 0) * 68 + row] = wv.x;
            ws[(kq * 4 + 1) * 68 + row] = wv.y;
            ws[(kq * 4 + 2) * 68 + row] = wv.z;
            ws[(kq * 4 + 3) * 68 + row] = wv.w;
        }
        __syncthreads();
#pragma unroll 8
        for (int k = 0; k < 64; ++k) {
            const float4 a4 = *(const float4*)&xs[k * 68 + ty * 4];
            const float4 b4 = *(const float4*)&ws[k * 68 + tx * 4];
            const float av[4] = {a4.x, a4.y, a4.z, a4.w};
#pragma unroll
            for (int i = 0; i < 4; ++i) {
                acc[i][0] = fmaf(av[i], b4.x, acc[i][0]);
                acc[i][1] = fmaf(av[i], b4.y, acc[i][1]);
                acc[i][2] = fmaf(av[i], b4.z, acc[i][2]);
                acc[i][3] = fmaf(av[i], b4.w, acc[i][3]);
            }
        }
        __syncthreads();
    }

    const float4 bb = *(const float4*)(Bv + tx * 4);
    float ss[4];
#pragma unroll
    for (int i = 0; i < 4; ++i) {
        acc[i][0] += bb.x; acc[i][1] += bb.y; acc[i][2] += bb.z; acc[i][3] += bb.w;
        float s = acc[i][0]*acc[i][0] + acc[i][1]*acc[i][1]
                + acc[i][2]*acc[i][2] + acc[i][3]*acc[i][3];
#pragma unroll
        for (int off = 1; off <= 8; off <<= 1)
            s += __shfl_xor(s, off, 64);
        ss[i] = s;
    }

    if (mat == 0) {
#pragma unroll
        for (int i = 0; i < 4; ++i) {
            const float inv = 1.0f / fmaxf(sqrtf(ss[i]), 1e-12f);
            float4 o;
            o.x = acc[i][0]*inv; o.y = acc[i][1]*inv; o.z = acc[i][2]*inv; o.w = acc[i][3]*inv;
            *(float4*)(subP + (size_t)(r0 + ty * 4 + i) * 64 + tx * 4) = o;
        }
    } else {
        __syncthreads();
#pragma unroll
        for (int i = 0; i < 4; ++i) {
            const float inv = 1.0f / fmaxf(sqrtf(ss[i]), 1e-12f);
#pragma unroll
            for (int j = 0; j < 4; ++j)
                tr[(tx * 4 + j) * 68 + ty * 4 + i] = acc[i][j] * inv;
        }
        __syncthreads();
#pragma unroll
        for (int i = 0; i < 4; ++i) {
            int e = t + 256 * i;
            int c = e >> 4, rq = e & 15;
            *(float4*)(edgeT + (size_t)c * 8192 + r0 + rq * 4) =
                *(const float4*)&tr[c * 68 + rq * 4];
        }
    }
}

// ---------------------------------------------------------------------------
// Kernel B (fused v3): scores GEMM + exact 1.5-entmax.
// Block = 8 rows x 8192 cols, 1024 threads, grid 1024.
// GEMM in TWO col-passes; per pass only acc[8] float4 (32 regs) is hot ->
// hot-loop live ~47 VGPR, no AGPR shuttling in the k-loop.
// z persisted as fp16 (self-consistent: tau solve and final p both use the
// rounded values): rows 0..2 -> LDS __half2 (48 KB), rows 3..7 -> 20 packed
// __half2 registers (cold; touched once/pass + ~5x in the tau iteration).
// tau: support-set iteration, exact quadratic solve per support, early break
// on block-uniform fixed point.
// ---------------------------------------------------------------------------
#define FMA4(ACC, S, B) \
    ACC.x = fmaf(S, B.x, ACC.x); ACC.y = fmaf(S, B.y, ACC.y); \
    ACC.z = fmaf(S, B.z, ACC.z); ACC.w = fmaf(S, B.w, ACC.w);

#define SCAN_ELEM(E, TAU) { \
    const float e_ = (E); \
    const bool p_ = e_ > (TAU); \
    const float zm_ = p_ ? e_ : 0.0f; \
    n  += p_ ? 1.0f : 0.0f; \
    s1 += zm_; \
    s2 = fmaf(zm_, e_, s2); }

__global__ __launch_bounds__(1024, 4) void fused_score_entmax_kernel(
    const float* __restrict__ subP, const float* __restrict__ edgeT,
    const float* __restrict__ log_scale, float* __restrict__ out)
{
    const int t    = threadIdx.x;
    const int lane = t & 63;
    const int wid  = t >> 6;
    const int r0   = blockIdx.x * 8;
    const int c0   = t * 4;

    __shared__ __half2 zH[3 * 4096];   // rows 0..2, both halves: 48 KB
    __shared__ float   asT[64 * 8];    // A fragment, k-major
    __shared__ float   tbl[16 * 24];   // per-wave reduce table
    __shared__ float   tauS[8];

    if (t < 512) {
        int r = t >> 6, k = t & 63;
        asT[k * 8 + r] = subP[(size_t)(r0 + r) * 64 + k];
    }
    __syncthreads();

    float sc = expf(log_scale[0]);
    sc = fminf(fmaxf(sc, 0.5f), 20.0f);
    const float zs = sc * 0.5f;        // z = scores/2

    __half2 zp[5][2][2];               // rows 3..7 [row][pass][pair]
    float pm[8];
#pragma unroll
    for (int r = 0; r < 8; ++r) pm[r] = -1e30f;

    for (int pass = 0; pass < 2; ++pass) {
        const int coff = pass * 4096;
        float4 acc[8];
#pragma unroll
        for (int r = 0; r < 8; ++r) acc[r] = make_float4(0.f, 0.f, 0.f, 0.f);
#pragma unroll 4
        for (int k = 0; k < 64; ++k) {
            const float4 b4 = *(const float4*)(edgeT + (size_t)k * 8192 + c0 + coff);
            const float4 a0 = *(const float4*)&asT[k * 8];
            const float4 a1 = *(const float4*)&asT[k * 8 + 4];
            FMA4(acc[0], a0.x, b4); FMA4(acc[1], a0.y, b4);
            FMA4(acc[2], a0.z, b4); FMA4(acc[3], a0.w, b4);
            FMA4(acc[4], a1.x, b4); FMA4(acc[5], a1.y, b4);
            FMA4(acc[6], a1.z, b4); FMA4(acc[7], a1.w, b4);
        }
        // epilogue: scale, round to fp16, track max of ROUNDED values
#pragma unroll
        for (int r = 0; r < 8; ++r) {
            __half2 h01, h23;
            h01.x = __float2half_rn(acc[r].x * zs);
            h01.y = __float2half_rn(acc[r].y * zs);
            h23.x = __float2half_rn(acc[r].z * zs);
            h23.y = __float2half_rn(acc[r].w * zs);
            const float f0 = __half2float(h01.x), f1 = __half2float(h01.y);
            const float f2 = __half2float(h23.x), f3 = __half2float(h23.y);
            pm[r] = fmaxf(pm[r], fmaxf(fmaxf(f0, f1), fmaxf(f2, f3)));
            if (r < 3) {
                __half2 pair[2] = {h01, h23};
                *(float2*)&zH[r * 4096 + t * 2 + pass * 2048] = *(const float2*)pair;
            } else {
                zp[r - 3][pass][0] = h01;
                zp[r - 3][pass][1] = h23;
            }
        }
    }

    // ---- per-row block max -> tau0 = max - 1 ----
#pragma unroll
    for (int r = 0; r < 8; ++r) {
#pragma unroll
        for (int off = 32; off; off >>= 1)
            pm[r] = fmaxf(pm[r], __shfl_xor(pm[r], off, 64));
    }
    if (lane == 0) {
#pragma unroll
        for (int r = 0; r < 8; ++r) tbl[wid * 24 + r] = pm[r];
    }
    __syncthreads();
    if (t < 8) {
        float m = -1e30f;
#pragma unroll
        for (int w = 0; w < 16; ++w) m = fmaxf(m, tbl[w * 24 + t]);
        tauS[t] = m - 1.0f;
    }
    __syncthreads();

    float tau[8];
#pragma unroll
    for (int r = 0; r < 8; ++r) tau[r] = tauS[r];

    // ---- support-set iteration on the fp16-rounded z ----
    for (int it = 0; it < ITERS; ++it) {
#pragma unroll
        for (int r = 0; r < 8; ++r) {
            float n = 0.f, s1 = 0.f, s2 = 0.f;
#pragma unroll
            for (int pass = 0; pass < 2; ++pass) {
                __half2 h01, h23;
                if (r < 3) {
                    float2 rd = *(const float2*)&zH[r * 4096 + t * 2 + pass * 2048];
                    const __half2* pp = (const __half2*)&rd;
                    h01 = pp[0]; h23 = pp[1];
                } else {
                    h01 = zp[r - 3][pass][0];
                    h23 = zp[r - 3][pass][1];
                }
                SCAN_ELEM(__half2float(h01.x), tau[r]);
                SCAN_ELEM(__half2float(h01.y), tau[r]);
                SCAN_ELEM(__half2float(h23.x), tau[r]);
                SCAN_ELEM(__half2float(h23.y), tau[r]);
            }
#pragma unroll
            for (int off = 32; off; off >>= 1) {
                n  += __shfl_xor(n,  off, 64);
                s1 += __shfl_xor(s1, off, 64);
                s2 += __shfl_xor(s2, off, 64);
            }
            if (lane == 0) {
                tbl[wid * 24 + r * 3 + 0] = n;
                tbl[wid * 24 + r * 3 + 1] = s1;
                tbl[wid * 24 + r * 3 + 2] = s2;
            }
        }
        __syncthreads();
        if (t < 8) {
            float n = 0.f, s1 = 0.f, s2 = 0.f;
#pragma unroll
            for (int w = 0; w < 16; ++w) {
                n  += tbl[w * 24 + t * 3 + 0];
                s1 += tbl[w * 24 + t * 3 + 1];
                s2 += tbl[w * 24 + t * 3 + 2];
            }
            const float tcur = tauS[t];
            const float disc = s1 * s1 - n * (s2 - 1.0f);
            float tn;
            if (disc >= 0.0f) {
                tn = (s1 - sqrtf(disc)) / n;        // exact solve on current support
            } else {
                const float g = s1 - n * tcur;      // > 0 (support nonempty)
                const float f = s2 - tcur * (2.0f * s1 - n * tcur);
                tn = tcur + (f - 1.0f) / (2.0f * g); // Newton fallback
            }
            tauS[t] = tn;
        }
        __syncthreads();
        bool same = true;
#pragma unroll
        for (int r = 0; r < 8; ++r) {
            const float nt = tauS[r];
            same &= (nt == tau[r]);
            tau[r] = nt;
        }
        if (same) break;    // block-uniform
    }

    // ---- p = max(z - tau, 0)^2, single coalesced write ----
#pragma unroll
    for (int r = 0; r < 8; ++r) {
        float* op = out + (size_t)(r0 + r) * 8192;
#pragma unroll
        for (int pass = 0; pass < 2; ++pass) {
            __half2 h01, h23;
            if (r < 3) {
                float2 rd = *(const float2*)&zH[r * 4096 + t * 2 + pass * 2048];
                const __half2* pp = (const __half2*)&rd;
                h01 = pp[0]; h23 = pp[1];
            } else {
                h01 = zp[r - 3][pass][0];
                h23 = zp[r - 3][pass][1];
            }
            float4 p4; float d;
            d = fmaxf(__half2float(h01.x) - tau[r], 0.f); p4.x = d * d;
            d = fmaxf(__half2float(h01.y) - tau[r], 0.f); p4.y = d * d;
            d = fmaxf(__half2float(h23.x) - tau[r], 0.f); p4.z = d * d;
            d = fmaxf(__half2float(h23.y) - tau[r], 0.f); p4.w = d * d;
            *(float4*)(op + c0 + pass * 4096) = p4;
        }
    }
}

// ---------------------------------------------------------------------------
extern "C" void kernel_launch(void* const* d_in, const int* in_sizes, int n_in,
                              void* d_out, int out_size, void* d_ws, size_t ws_size,
                              hipStream_t stream)
{
    const float* edge_repr = (const float*)d_in[0];
    const float* sub_repr  = (const float*)d_in[1];
    const float* W_sub     = (const float*)d_in[2];
    const float* b_sub     = (const float*)d_in[3];
    const float* W_edge    = (const float*)d_in[4];
    const float* b_edge    = (const float*)d_in[5];
    const float* log_scale = (const float*)d_in[6];
    float* out = (float*)d_out;

    float* sub_proj = (float*)d_ws;                      // [8192][64]  row-major
    float* edgeT    = (float*)d_ws + (size_t)8192 * 64;  // [64][8192]  k-major

    proj_norm_kernel<<<dim3(128, 2), 256, 0, stream>>>(
        sub_repr, edge_repr, W_sub, b_sub, W_edge, b_edge, sub_proj, edgeT);

    fused_score_entmax_kernel<<<1024, 1024, 0, stream>>>(
        sub_proj, edgeT, log_scale, out);
}

// Round 5
// 488.743 us; speedup vs baseline: 1.4657x; 1.4657x over previous
//
#include <hip/hip_runtime.h>
#include <hip/hip_fp16.h>
#include <math.h>

#define ITERS 12

// ---------------------------------------------------------------------------
// Kernel A: P = l2_normalize(X @ W^T + b) for both matrices.
// 32-row tiles, grid (256,2), block 256 (16x16, 2x4 micro-tile).
// 2 blocks/CU (vs 1 before) -> latency hiding. Outputs: subP [8192][64]
// row-major; edgeT [64][8192] k-major (via LDS transpose).
// ---------------------------------------------------------------------------
__global__ __launch_bounds__(256) void proj_norm_kernel(
    const float* __restrict__ Xsub, const float* __restrict__ Xedge,
    const float* __restrict__ Wsub, const float* __restrict__ bsub,
    const float* __restrict__ Wedge, const float* __restrict__ bedge,
    float* __restrict__ subP, float* __restrict__ edgeT)
{
    const int mat = blockIdx.y;
    const float* X  = mat ? Xedge : Xsub;
    const float* W  = mat ? Wedge : Wsub;
    const float* Bv = mat ? bedge : bsub;

    const int r0 = blockIdx.x * 32;
    const int t  = threadIdx.x;
    const int tx = t & 15, ty = t >> 4;

    __shared__ float xs[64 * 34];   // [k][row(32)+pad]
    __shared__ float ws[64 * 68];   // [k][col(64)+pad]
    __shared__ float tr[64 * 36];   // [col][row] transpose staging (36: f4-aligned)

    float acc[2][4] = {};

    for (int ch = 0; ch < 8; ++ch) {
        const int kb = ch * 64;
#pragma unroll
        for (int i = 0; i < 2; ++i) {
            int e = t + 256 * i;            // 512 float4 (32 rows x 16 kq)
            int row = e & 31, kq = e >> 5;
            float4 xv = *(const float4*)(X + (size_t)(r0 + row) * 512 + kb + kq * 4);
            xs[(kq * 4 + 0) * 34 + row] = xv.x;
            xs[(kq * 4 + 1) * 34 + row] = xv.y;
            xs[(kq * 4 + 2) * 34 + row] = xv.z;
            xs[(kq * 4 + 3) * 34 + row] = xv.w;
        }
#pragma unroll
        for (int i = 0; i < 4; ++i) {
            int e = t + 256 * i;            // 1024 float4 (64 cols x 16 kq)
            int col = e & 63, kq = e >> 6;
            float4 wv = *(const float4*)(W + (size_t)col * 512 + kb + kq * 4);
            ws[(kq * 4 + 0) * 68 + col] = wv.x;
            ws[(kq * 4 + 1) * 68 + col] = wv.y;
            ws[(kq * 4 + 2) * 68 + col] = wv.z;
            ws[(kq * 4 + 3) * 68 + col] = wv.w;
        }
        __syncthreads();
#pragma unroll 8
        for (int k = 0; k < 64; ++k) {
            const float2 a2 = *(const float2*)&xs[k * 34 + ty * 2];
            const float4 b4 = *(const float4*)&ws[k * 68 + tx * 4];
            acc[0][0] = fmaf(a2.x, b4.x, acc[0][0]);
            acc[0][1] = fmaf(a2.x, b4.y, acc[0][1]);
            acc[0][2] = fmaf(a2.x, b4.z, acc[0][2]);
            acc[0][3] = fmaf(a2.x, b4.w, acc[0][3]);
            acc[1][0] = fmaf(a2.y, b4.x, acc[1][0]);
            acc[1][1] = fmaf(a2.y, b4.y, acc[1][1]);
            acc[1][2] = fmaf(a2.y, b4.z, acc[1][2]);
            acc[1][3] = fmaf(a2.y, b4.w, acc[1][3]);
        }
        __syncthreads();
    }

    // bias + rowwise l2 norm: row's 64 cols live in lanes sharing ty ->
    // shfl_xor over lane bits 0..3.
    const float4 bb = *(const float4*)(Bv + tx * 4);
    float inv_[2];
#pragma unroll
    for (int i = 0; i < 2; ++i) {
        acc[i][0] += bb.x; acc[i][1] += bb.y; acc[i][2] += bb.z; acc[i][3] += bb.w;
        float s = acc[i][0]*acc[i][0] + acc[i][1]*acc[i][1]
                + acc[i][2]*acc[i][2] + acc[i][3]*acc[i][3];
#pragma unroll
        for (int off = 1; off <= 8; off <<= 1)
            s += __shfl_xor(s, off, 64);
        inv_[i] = 1.0f / fmaxf(sqrtf(s), 1e-12f);
    }

    if (mat == 0) {
#pragma unroll
        for (int i = 0; i < 2; ++i) {
            float4 o;
            o.x = acc[i][0]*inv_[i]; o.y = acc[i][1]*inv_[i];
            o.z = acc[i][2]*inv_[i]; o.w = acc[i][3]*inv_[i];
            *(float4*)(subP + (size_t)(r0 + ty * 2 + i) * 64 + tx * 4) = o;
        }
    } else {
        __syncthreads();
#pragma unroll
        for (int i = 0; i < 2; ++i)
#pragma unroll
            for (int j = 0; j < 4; ++j)
                tr[(tx * 4 + j) * 36 + ty * 2 + i] = acc[i][j] * inv_[i];
        __syncthreads();
#pragma unroll
        for (int i = 0; i < 2; ++i) {
            int e = t + 256 * i;            // 512 float4 (64 cols x 8 row-quads)
            int c = e >> 3, rq = e & 7;
            *(float4*)(edgeT + (size_t)c * 8192 + r0 + rq * 4) =
                *(const float4*)&tr[c * 36 + rq * 4];
        }
    }
}

// ---------------------------------------------------------------------------
// Kernel B1: z[s][e] = fp16( (subP[s] . edgeP[e]) * scale / 2 ).
// 64x64 tiles, K=64 fully in LDS, 4x4 micro-tile (16 acc regs -> no
// register pressure). 34 KB LDS -> 4 blocks/CU. Grid (128,128).
// ---------------------------------------------------------------------------
__global__ __launch_bounds__(256) void score_gemm_fp16_kernel(
    const float* __restrict__ subP, const float* __restrict__ edgeT,
    const float* __restrict__ log_scale, __half* __restrict__ z)
{
    const int t  = threadIdx.x;
    const int tx = t & 15, ty = t >> 4;
    const int s0 = blockIdx.y * 64;
    const int e0 = blockIdx.x * 64;

    __shared__ float as[64 * 68];   // [k][s+pad]
    __shared__ float bs[64 * 68];   // [k][e+pad]

#pragma unroll
    for (int i = 0; i < 4; ++i) {
        int e = t + 256 * i;            // A: 64 rows x 16 kq
        int row = e & 63, kq = e >> 6;
        float4 v = *(const float4*)(subP + (size_t)(s0 + row) * 64 + kq * 4);
        as[(kq * 4 + 0) * 68 + row] = v.x;
        as[(kq * 4 + 1) * 68 + row] = v.y;
        as[(kq * 4 + 2) * 68 + row] = v.z;
        as[(kq * 4 + 3) * 68 + row] = v.w;
    }
#pragma unroll
    for (int i = 0; i < 4; ++i) {
        int e = t + 256 * i;            // B: 64 k x 16 col-quads (already k-major)
        int k = e >> 4, cq = e & 15;
        *(float4*)&bs[k * 68 + cq * 4] =
            *(const float4*)(edgeT + (size_t)k * 8192 + e0 + cq * 4);
    }
    __syncthreads();

    float acc[4][4] = {};
#pragma unroll 8
    for (int k = 0; k < 64; ++k) {
        const float4 a4 = *(const float4*)&as[k * 68 + ty * 4];
        const float4 b4 = *(const float4*)&bs[k * 68 + tx * 4];
        const float av[4] = {a4.x, a4.y, a4.z, a4.w};
#pragma unroll
        for (int i = 0; i < 4; ++i) {
            acc[i][0] = fmaf(av[i], b4.x, acc[i][0]);
            acc[i][1] = fmaf(av[i], b4.y, acc[i][1]);
            acc[i][2] = fmaf(av[i], b4.z, acc[i][2]);
            acc[i][3] = fmaf(av[i], b4.w, acc[i][3]);
        }
    }

    float sc = expf(log_scale[0]);
    sc = fminf(fmaxf(sc, 0.5f), 20.0f);
    const float zs = sc * 0.5f;         // z = scores/2

#pragma unroll
    for (int i = 0; i < 4; ++i) {
        __half2 h0, h1;
        h0.x = __float2half_rn(acc[i][0] * zs);
        h0.y = __float2half_rn(acc[i][1] * zs);
        h1.x = __float2half_rn(acc[i][2] * zs);
        h1.y = __float2half_rn(acc[i][3] * zs);
        __half2 pair[2] = {h0, h1};
        *(float2*)(z + (size_t)(s0 + ty * 4 + i) * 8192 + e0 + tx * 4) =
            *(const float2*)pair;
    }
}

// ---------------------------------------------------------------------------
// Kernel B2: rowwise exact 1.5-entmax on fp16 z (self-consistent: tau solved
// on the same rounded values used for p). One block (256 thr) per row; 32 z
// per thread unpacked to fp32 registers. Support-set iteration with exact
// quadratic solve, block-uniform early break. ~40 regs -> full occupancy.
// ---------------------------------------------------------------------------
__global__ __launch_bounds__(256) void entmax_fp16_kernel(
    const __half* __restrict__ z, float* __restrict__ out)
{
    const int row  = blockIdx.x;
    const int t    = threadIdx.x;
    const int lane = t & 63, wid = t >> 6;
    const __half* zr = z + (size_t)row * 8192;

    // 4 chunks of 8 cols: cols c*2048 + t*8 .. +7 (fully coalesced f4 loads)
    float4 rd[4];
#pragma unroll
    for (int c = 0; c < 4; ++c)
        rd[c] = *(const float4*)(zr + c * 2048 + t * 8);

    float zv[32];
#pragma unroll
    for (int c = 0; c < 4; ++c) {
        const __half2* p = (const __half2*)&rd[c];
#pragma unroll
        for (int j = 0; j < 4; ++j) {
            float2 f2 = __half22float2(p[j]);
            zv[c * 8 + j * 2 + 0] = f2.x;
            zv[c * 8 + j * 2 + 1] = f2.y;
        }
    }

    __shared__ float tblm[4];
    __shared__ float tbl[2][4][3];

    float m = -1e30f;
#pragma unroll
    for (int i = 0; i < 32; ++i) m = fmaxf(m, zv[i]);
#pragma unroll
    for (int off = 32; off; off >>= 1) m = fmaxf(m, __shfl_xor(m, off, 64));
    if (lane == 0) tblm[wid] = m;
    __syncthreads();
    m = fmaxf(fmaxf(tblm[0], tblm[1]), fmaxf(tblm[2], tblm[3]));

    float tau = m - 1.0f;   // f(tau0) >= 1 (max element alone contributes 1)

    for (int it = 0; it < ITERS; ++it) {
        float n = 0.f, s1 = 0.f, s2 = 0.f;
#pragma unroll
        for (int i = 0; i < 32; ++i) {
            const float e_  = zv[i];
            const bool  p_  = e_ > tau;
            const float zm_ = p_ ? e_ : 0.0f;
            n  += p_ ? 1.0f : 0.0f;
            s1 += zm_;
            s2  = fmaf(zm_, e_, s2);
        }
#pragma unroll
        for (int off = 32; off; off >>= 1) {
            n  += __shfl_xor(n,  off, 64);
            s1 += __shfl_xor(s1, off, 64);
            s2 += __shfl_xor(s2, off, 64);
        }
        if (lane == 0) {
            tbl[it & 1][wid][0] = n;
            tbl[it & 1][wid][1] = s1;
            tbl[it & 1][wid][2] = s2;
        }
        __syncthreads();
        float N = 0.f, S1 = 0.f, S2 = 0.f;
#pragma unroll
        for (int w = 0; w < 4; ++w) {
            N  += tbl[it & 1][w][0];
            S1 += tbl[it & 1][w][1];
            S2 += tbl[it & 1][w][2];
        }
        // all threads compute identically (same LDS inputs, same op order)
        const float disc = S1 * S1 - N * (S2 - 1.0f);
        float tn;
        if (disc >= 0.0f) {
            tn = (S1 - sqrtf(disc)) / N;       // exact solve on current support
        } else {
            const float g = S1 - N * tau;      // > 0 (support nonempty)
            const float f = S2 - tau * (2.0f * S1 - N * tau);
            tn = tau + (f - 1.0f) / (2.0f * g);
        }
        if (tn == tau) break;                  // block-uniform fixed point
        tau = tn;
    }

    // p = max(z - tau, 0)^2
#pragma unroll
    for (int c = 0; c < 4; ++c) {
        float4 p0, p1; float d;
        d = fmaxf(zv[c*8+0] - tau, 0.f); p0.x = d * d;
        d = fmaxf(zv[c*8+1] - tau, 0.f); p0.y = d * d;
        d = fmaxf(zv[c*8+2] - tau, 0.f); p0.z = d * d;
        d = fmaxf(zv[c*8+3] - tau, 0.f); p0.w = d * d;
        d = fmaxf(zv[c*8+4] - tau, 0.f); p1.x = d * d;
        d = fmaxf(zv[c*8+5] - tau, 0.f); p1.y = d * d;
        d = fmaxf(zv[c*8+6] - tau, 0.f); p1.z = d * d;
        d = fmaxf(zv[c*8+7] - tau, 0.f); p1.w = d * d;
        float* op = out + (size_t)row * 8192 + c * 2048 + t * 8;
        *(float4*)op       = p0;
        *(float4*)(op + 4) = p1;
    }
}

// ---------------------------------------------------------------------------
extern "C" void kernel_launch(void* const* d_in, const int* in_sizes, int n_in,
                              void* d_out, int out_size, void* d_ws, size_t ws_size,
                              hipStream_t stream)
{
    const float* edge_repr = (const float*)d_in[0];
    const float* sub_repr  = (const float*)d_in[1];
    const float* W_sub     = (const float*)d_in[2];
    const float* b_sub     = (const float*)d_in[3];
    const float* W_edge    = (const float*)d_in[4];
    const float* b_edge    = (const float*)d_in[5];
    const float* log_scale = (const float*)d_in[6];
    float* out = (float*)d_out;

    float*  sub_proj = (float*)d_ws;                       // 2 MB
    float*  edgeT    = (float*)d_ws + (size_t)8192 * 64;   // 2 MB, k-major
    __half* zbuf     = (__half*)((float*)d_ws + (size_t)2 * 8192 * 64);  // 134 MB

    proj_norm_kernel<<<dim3(256, 2), 256, 0, stream>>>(
        sub_repr, edge_repr, W_sub, b_sub, W_edge, b_edge, sub_proj, edgeT);

    score_gemm_fp16_kernel<<<dim3(128, 128), 256, 0, stream>>>(
        sub_proj, edgeT, log_scale, zbuf);

    entmax_fp16_kernel<<<8192, 256, 0, stream>>>(zbuf, out);
}

// Round 7
// 419.377 us; speedup vs baseline: 1.7081x; 1.1654x over previous
//
#include <hip/hip_runtime.h>
#include <hip/hip_fp16.h>
#include <math.h>

#define ITERS 12

typedef __attribute__((ext_vector_type(8))) short short8;
typedef __attribute__((ext_vector_type(4))) float float4v;

static __device__ inline unsigned short f2bf(float f) {
    union { float f; unsigned int u; } c; c.f = f;
    unsigned int u = c.u;
    u += 0x7fffu + ((u >> 16) & 1u);          // round-to-nearest-even
    return (unsigned short)(u >> 16);
}
static __device__ inline float bf2f(unsigned short h) {
    union { float f; unsigned int u; } c; c.u = ((unsigned int)h) << 16;
    return c.f;
}

// ---------------------------------------------------------------------------
// Kernel A: P = l2_normalize(X @ W^T + b), emitted as split-bf16 rows of 192:
//   sub:  [hi(64) | lo(64) | hi(64)]
//   edge: [hi(64) | hi(64) | lo(64)]
// so that subE @ edgeE^T over K=192 = Ah*Bh + Al*Bh + Ah*Bl (lo*lo dropped,
// <= 64*2^-18 ~ 2.4e-4). 32-row tiles, grid (256,2), block 256, 2x4 micro.
// ---------------------------------------------------------------------------
__global__ __launch_bounds__(256) void proj_norm_kernel(
    const float* __restrict__ Xsub, const float* __restrict__ Xedge,
    const float* __restrict__ Wsub, const float* __restrict__ bsub,
    const float* __restrict__ Wedge, const float* __restrict__ bedge,
    unsigned short* __restrict__ subE, unsigned short* __restrict__ edgeE)
{
    const int mat = blockIdx.y;
    const float* X  = mat ? Xedge : Xsub;
    const float* W  = mat ? Wedge : Wsub;
    const float* Bv = mat ? bedge : bsub;
    unsigned short* OUT = mat ? edgeE : subE;

    const int r0 = blockIdx.x * 32;
    const int t  = threadIdx.x;
    const int tx = t & 15, ty = t >> 4;

    __shared__ float xs[64 * 34];   // [k][row(32)+pad]
    __shared__ float ws[64 * 68];   // [k][col(64)+pad]

    float acc[2][4] = {};

    for (int ch = 0; ch < 8; ++ch) {
        const int kb = ch * 64;
#pragma unroll
        for (int i = 0; i < 2; ++i) {
            int e = t + 256 * i;            // 512 float4 (32 rows x 16 kq)
            int row = e & 31, kq = e >> 5;
            float4 xv = *(const float4*)(X + (size_t)(r0 + row) * 512 + kb + kq * 4);
            xs[(kq * 4 + 0) * 34 + row] = xv.x;
            xs[(kq * 4 + 1) * 34 + row] = xv.y;
            xs[(kq * 4 + 2) * 34 + row] = xv.z;
            xs[(kq * 4 + 3) * 34 + row] = xv.w;
        }
#pragma unroll
        for (int i = 0; i < 4; ++i) {
            int e = t + 256 * i;            // 1024 float4 (64 cols x 16 kq)
            int col = e & 63, kq = e >> 6;
            float4 wv = *(const float4*)(W + (size_t)col * 512 + kb + kq * 4);
            ws[(kq * 4 + 0) * 68 + col] = wv.x;
            ws[(kq * 4 + 1) * 68 + col] = wv.y;
            ws[(kq * 4 + 2) * 68 + col] = wv.z;
            ws[(kq * 4 + 3) * 68 + col] = wv.w;
        }
        __syncthreads();
#pragma unroll 8
        for (int k = 0; k < 64; ++k) {
            const float2 a2 = *(const float2*)&xs[k * 34 + ty * 2];
            const float4 b4 = *(const float4*)&ws[k * 68 + tx * 4];
            acc[0][0] = fmaf(a2.x, b4.x, acc[0][0]);
            acc[0][1] = fmaf(a2.x, b4.y, acc[0][1]);
            acc[0][2] = fmaf(a2.x, b4.z, acc[0][2]);
            acc[0][3] = fmaf(a2.x, b4.w, acc[0][3]);
            acc[1][0] = fmaf(a2.y, b4.x, acc[1][0]);
            acc[1][1] = fmaf(a2.y, b4.y, acc[1][1]);
            acc[1][2] = fmaf(a2.y, b4.z, acc[1][2]);
            acc[1][3] = fmaf(a2.y, b4.w, acc[1][3]);
        }
        __syncthreads();
    }

    const float4 bb = *(const float4*)(Bv + tx * 4);
#pragma unroll
    for (int i = 0; i < 2; ++i) {
        acc[i][0] += bb.x; acc[i][1] += bb.y; acc[i][2] += bb.z; acc[i][3] += bb.w;
        float s = acc[i][0]*acc[i][0] + acc[i][1]*acc[i][1]
                + acc[i][2]*acc[i][2] + acc[i][3]*acc[i][3];
#pragma unroll
        for (int off = 1; off <= 8; off <<= 1)
            s += __shfl_xor(s, off, 64);
        const float inv = 1.0f / fmaxf(sqrtf(s), 1e-12f);

        unsigned short h[4], l[4];
#pragma unroll
        for (int j = 0; j < 4; ++j) {
            const float v = acc[i][j] * inv;
            h[j] = f2bf(v);
            l[j] = f2bf(v - bf2f(h[j]));
        }
        uint2 hp, lp;
        hp.x = (unsigned)h[0] | ((unsigned)h[1] << 16);
        hp.y = (unsigned)h[2] | ((unsigned)h[3] << 16);
        lp.x = (unsigned)l[0] | ((unsigned)l[1] << 16);
        lp.y = (unsigned)l[2] | ((unsigned)l[3] << 16);

        unsigned short* base = OUT + (size_t)(r0 + ty * 2 + i) * 192 + tx * 4;
        *(uint2*)(base)       = hp;
        *(uint2*)(base + 64)  = mat ? hp : lp;   // edge: hi ; sub: lo
        *(uint2*)(base + 128) = mat ? lp : hp;   // edge: lo ; sub: hi
    }
}

// ---------------------------------------------------------------------------
// Kernel B1 (MFMA): z[s][e] = fp16( (subP[s].edgeP[e]) * scale / 2 ) via
// bf16 GEMM over extended K=192. Tile 128(s) x 64(e), grid (128, 64),
// 256 thr (4 waves). Wave covers mrow0=(wid&1)*64 (4 m-tiles of 16) x
// ncol0=(wid>>1)*32 (2 n-tiles of 16): 4 waves = full 128x64.  [r6 bug:
// 128x128 tile left cols 64-127 unwritten -> poison; fixed by shrinking.]
// K staged in 3 chunks of 64 (LDS stride 72 -> 16B-aligned b128, 27 KB).
// Fragment layouts (m89/m92/m97 gemm_bt pattern): A and B^T rows loaded
// identically, A[m=lane&15][k=quad*8+j]; C/D col=lane&15, row=quad*4+reg.
// ---------------------------------------------------------------------------
__global__ __launch_bounds__(256, 4) void score_mfma_kernel(
    const unsigned short* __restrict__ subE,
    const unsigned short* __restrict__ edgeE,
    const float* __restrict__ log_scale, __half* __restrict__ z)
{
    const int t    = threadIdx.x;
    const int lane = t & 63;
    const int wid  = t >> 6;
    const int li   = lane & 15;
    const int quad = lane >> 4;
    const int s0   = blockIdx.y * 128;
    const int e0   = blockIdx.x * 64;
    const int mrow0 = (wid & 1) * 64;
    const int ncol0 = (wid >> 1) * 32;

    __shared__ unsigned short aS[128 * 72];
    __shared__ unsigned short bS[64 * 72];

    float4v acc[4][2];
#pragma unroll
    for (int mi = 0; mi < 4; ++mi)
#pragma unroll
        for (int ni = 0; ni < 2; ++ni)
            acc[mi][ni] = (float4v){0.f, 0.f, 0.f, 0.f};

    for (int c = 0; c < 3; ++c) {
        if (c) __syncthreads();             // protect LDS reuse
#pragma unroll
        for (int i = 0; i < 4; ++i) {
            int e = t + 256 * i;            // 1024 f4 (128 rows x 8 offs)
            int row = e >> 3, off = e & 7;
            *(float4*)&aS[row * 72 + off * 8] =
                *(const float4*)(subE + (size_t)(s0 + row) * 192 + c * 64 + off * 8);
        }
#pragma unroll
        for (int i = 0; i < 2; ++i) {
            int e = t + 256 * i;            // 512 f4 (64 rows x 8 offs)
            int row = e >> 3, off = e & 7;
            *(float4*)&bS[row * 72 + off * 8] =
                *(const float4*)(edgeE + (size_t)(e0 + row) * 192 + c * 64 + off * 8);
        }
        __syncthreads();

#pragma unroll
        for (int ks = 0; ks < 2; ++ks) {
            short8 af[4], bf[2];
#pragma unroll
            for (int mi = 0; mi < 4; ++mi)
                af[mi] = *(const short8*)&aS[(mrow0 + mi * 16 + li) * 72 + ks * 32 + quad * 8];
#pragma unroll
            for (int ni = 0; ni < 2; ++ni)
                bf[ni] = *(const short8*)&bS[(ncol0 + ni * 16 + li) * 72 + ks * 32 + quad * 8];
#pragma unroll
            for (int mi = 0; mi < 4; ++mi)
#pragma unroll
                for (int ni = 0; ni < 2; ++ni)
                    acc[mi][ni] = __builtin_amdgcn_mfma_f32_16x16x32_bf16(
                        af[mi], bf[ni], acc[mi][ni], 0, 0, 0);
        }
    }

    float sc = expf(log_scale[0]);
    sc = fminf(fmaxf(sc, 0.5f), 20.0f);
    const float zs = sc * 0.5f;             // z = scores/2

#pragma unroll
    for (int mi = 0; mi < 4; ++mi)
#pragma unroll
        for (int ni = 0; ni < 2; ++ni) {
            const int col = e0 + ncol0 + ni * 16 + li;
#pragma unroll
            for (int reg = 0; reg < 4; ++reg) {
                const int row = s0 + mrow0 + mi * 16 + quad * 4 + reg;
                z[(size_t)row * 8192 + col] = __float2half_rn(acc[mi][ni][reg] * zs);
            }
        }
}

// ---------------------------------------------------------------------------
// Kernel B2: rowwise exact 1.5-entmax on fp16 z (unchanged r5). One block
// per row, 32 z/thread in fp32 regs, support-set iteration w/ exact
// quadratic solve + block-uniform early break.
// ---------------------------------------------------------------------------
__global__ __launch_bounds__(256) void entmax_fp16_kernel(
    const __half* __restrict__ z, float* __restrict__ out)
{
    const int row  = blockIdx.x;
    const int t    = threadIdx.x;
    const int lane = t & 63, wid = t >> 6;
    const __half* zr = z + (size_t)row * 8192;

    float4 rd[4];
#pragma unroll
    for (int c = 0; c < 4; ++c)
        rd[c] = *(const float4*)(zr + c * 2048 + t * 8);

    float zv[32];
#pragma unroll
    for (int c = 0; c < 4; ++c) {
        const __half2* p = (const __half2*)&rd[c];
#pragma unroll
        for (int j = 0; j < 4; ++j) {
            float2 f2 = __half22float2(p[j]);
            zv[c * 8 + j * 2 + 0] = f2.x;
            zv[c * 8 + j * 2 + 1] = f2.y;
        }
    }

    __shared__ float tblm[4];
    __shared__ float tbl[2][4][3];

    float m = -1e30f;
#pragma unroll
    for (int i = 0; i < 32; ++i) m = fmaxf(m, zv[i]);
#pragma unroll
    for (int off = 32; off; off >>= 1) m = fmaxf(m, __shfl_xor(m, off, 64));
    if (lane == 0) tblm[wid] = m;
    __syncthreads();
    m = fmaxf(fmaxf(tblm[0], tblm[1]), fmaxf(tblm[2], tblm[3]));

    float tau = m - 1.0f;

    for (int it = 0; it < ITERS; ++it) {
        float n = 0.f, s1 = 0.f, s2 = 0.f;
#pragma unroll
        for (int i = 0; i < 32; ++i) {
            const float e_  = zv[i];
            const bool  p_  = e_ > tau;
            const float zm_ = p_ ? e_ : 0.0f;
            n  += p_ ? 1.0f : 0.0f;
            s1 += zm_;
            s2  = fmaf(zm_, e_, s2);
        }
#pragma unroll
        for (int off = 32; off; off >>= 1) {
            n  += __shfl_xor(n,  off, 64);
            s1 += __shfl_xor(s1, off, 64);
            s2 += __shfl_xor(s2, off, 64);
        }
        if (lane == 0) {
            tbl[it & 1][wid][0] = n;
            tbl[it & 1][wid][1] = s1;
            tbl[it & 1][wid][2] = s2;
        }
        __syncthreads();
        float N = 0.f, S1 = 0.f, S2 = 0.f;
#pragma unroll
        for (int w = 0; w < 4; ++w) {
            N  += tbl[it & 1][w][0];
            S1 += tbl[it & 1][w][1];
            S2 += tbl[it & 1][w][2];
        }
        const float disc = S1 * S1 - N * (S2 - 1.0f);
        float tn;
        if (disc >= 0.0f) {
            tn = (S1 - sqrtf(disc)) / N;
        } else {
            const float g = S1 - N * tau;
            const float f = S2 - tau * (2.0f * S1 - N * tau);
            tn = tau + (f - 1.0f) / (2.0f * g);
        }
        if (tn == tau) break;
        tau = tn;
    }

#pragma unroll
    for (int c = 0; c < 4; ++c) {
        float4 p0, p1; float d;
        d = fmaxf(zv[c*8+0] - tau, 0.f); p0.x = d * d;
        d = fmaxf(zv[c*8+1] - tau, 0.f); p0.y = d * d;
        d = fmaxf(zv[c*8+2] - tau, 0.f); p0.z = d * d;
        d = fmaxf(zv[c*8+3] - tau, 0.f); p0.w = d * d;
        d = fmaxf(zv[c*8+4] - tau, 0.f); p1.x = d * d;
        d = fmaxf(zv[c*8+5] - tau, 0.f); p1.y = d * d;
        d = fmaxf(zv[c*8+6] - tau, 0.f); p1.z = d * d;
        d = fmaxf(zv[c*8+7] - tau, 0.f); p1.w = d * d;
        float* op = out + (size_t)row * 8192 + c * 2048 + t * 8;
        *(float4*)op       = p0;
        *(float4*)(op + 4) = p1;
    }
}

// ---------------------------------------------------------------------------
extern "C" void kernel_launch(void* const* d_in, const int* in_sizes, int n_in,
                              void* d_out, int out_size, void* d_ws, size_t ws_size,
                              hipStream_t stream)
{
    const float* edge_repr = (const float*)d_in[0];
    const float* sub_repr  = (const float*)d_in[1];
    const float* W_sub     = (const float*)d_in[2];
    const float* b_sub     = (const float*)d_in[3];
    const float* W_edge    = (const float*)d_in[4];
    const float* b_edge    = (const float*)d_in[5];
    const float* log_scale = (const float*)d_in[6];
    float* out = (float*)d_out;

    unsigned short* subE  = (unsigned short*)d_ws;                 // 3 MB
    unsigned short* edgeE = subE + (size_t)8192 * 192;             // 3 MB
    __half*         zbuf  = (__half*)(edgeE + (size_t)8192 * 192); // 134 MB

    proj_norm_kernel<<<dim3(256, 2), 256, 0, stream>>>(
        sub_repr, edge_repr, W_sub, b_sub, W_edge, b_edge, subE, edgeE);

    score_mfma_kernel<<<dim3(128, 64), 256, 0, stream>>>(
        subE, edgeE, log_scale, zbuf);

    entmax_fp16_kernel<<<8192, 256, 0, stream>>>(zbuf, out);
}